// Round 2
// baseline (716.864 us; speedup 1.0000x reference)
//
#include <hip/hip_runtime.h>
#include <hip/hip_bf16.h>
#include <math.h>

// ---------------- problem constants ----------------
#define BSZ   8
#define LSEQ  107
#define NNF   17
#define NEF   9
#define NH    128
#define EHD   32
#define H3D   32
#define NLAY  10
#define PCD   32
#define TLAY  3
#define THD   8
#define FFD   256
#define NCLS  3
#define DD    160          // NH + PC
#define HDD   20           // D / TH
#define NND   856          // nodes
#define NPAD  896          // padded to 14*64 for GEMM
#define NE    2896         // edges
#define NSEQ  1696         // seq edges
#define NCOLS 4352         // 4096 (msg) + 128 (b2 part) + 128 (root part)
#define NCT   68           // 4352 / 64 column tiles

typedef __bf16 bf16;
typedef __bf16 bf16x8 __attribute__((ext_vector_type(8)));
typedef float  f32x4  __attribute__((ext_vector_type(4)));

__device__ __forceinline__ float geluf(float z) {
    return 0.5f * z * (1.0f + erff(z * 0.70710678118654752f));
}
__device__ __forceinline__ float wred(float v) {
    #pragma unroll
    for (int o = 32; o; o >>= 1) v += __shfl_xor(v, o, 64);
    return v;
}

// ---------------- ChebConv helpers ----------------
__global__ void k_deg(const int* sei, float* deg) {
    int e = blockIdx.x * 256 + threadIdx.x;
    if (e < NSEQ) atomicAdd(&deg[sei[e]], 1.0f);
}
__global__ void k_w(const int* sei, const float* deg, float* w) {
    int e = blockIdx.x * 256 + threadIdx.x;
    if (e >= NSEQ) return;
    int s = sei[e], d = sei[NSEQ + e];
    float ds = deg[s], dd = deg[d];
    float is = ds > 0.f ? rsqrtf(fmaxf(ds, 1e-12f)) : 0.f;
    float id = dd > 0.f ? rsqrtf(fmaxf(dd, 1e-12f)) : 0.f;
    w[e] = -(is * id);
}
__global__ void k_lap(const int* sei, const float* w, const float* x, float* out) {
    int idx = blockIdx.x * 256 + threadIdx.x;
    if (idx >= NSEQ * NNF) return;
    int e = idx / NNF, f = idx - e * NNF;
    int s = sei[e], d = sei[NSEQ + e];
    atomicAdd(&out[d * NNF + f], w[e] * x[s * NNF + f]);
}
// h0 = x@cw0 + tx1@cw1 + (2*lap(tx1)-x)@cw2 + cheb_b
__global__ void k_cheb(const float* x, const float* tx1, const float* txt,
                       const float* cw, const float* cb, float* h0) {
    int n = blockIdx.x, o = threadIdx.x;
    float acc = cb[o];
    #pragma unroll
    for (int f = 0; f < NNF; ++f) {
        float xv = x[n * NNF + f];
        float t1 = tx1[n * NNF + f];
        float t2 = 2.f * txt[n * NNF + f] - xv;
        acc += xv * cw[f * NH + o]
             + t1 * cw[NNF * NH + f * NH + o]
             + t2 * cw[2 * NNF * NH + f * NH + o];
    }
    h0[n * NH + o] = acc;
}

// ---------------- edge encoder + all-layer t1 ----------------
__global__ void k_ea(const float* eattr, const float* eew, const float* eeb, float* ea) {
    int idx = blockIdx.x * 256 + threadIdx.x;
    if (idx >= NE * EHD) return;
    int e = idx >> 5, c = idx & 31;
    float acc = eeb[c];
    #pragma unroll
    for (int f = 0; f < NEF; ++f) acc += eattr[e * NEF + f] * eew[f * EHD + c];
    ea[idx] = acc;
}
__global__ void k_t1(const float* ea, const float* w1, const float* b1, float* t1) {
    int idx = blockIdx.x * 256 + threadIdx.x;
    if (idx >= NLAY * NE * H3D) return;
    int c = idx & 31;
    int le = idx >> 5;
    int e = le % NE, l = le / NE;
    float acc = b1[l * H3D + c];
    #pragma unroll
    for (int j = 0; j < EHD; ++j) acc += ea[e * EHD + j] * w1[(l * EHD + j) * H3D + c];
    t1[idx] = acc;
}

// ---------------- pack B: [l][col][k] bf16; col = j*128+o | 4096+o (b2) | 4224+o (root) ----------------
__global__ void k_pack(const float* w2, const float* b2, const float* rootw, bf16* bp) {
    __shared__ bf16 t[64][65];
    int l = blockIdx.z, ct = blockIdx.y, kt = blockIdx.x;
    int tid = threadIdx.x;
    int cc = tid & 63, rr = tid >> 6;
    int colbase = ct * 64;
    #pragma unroll
    for (int rep = 0; rep < 16; ++rep) {
        int kk = rep * 4 + rr;
        int k = kt * 64 + kk;
        int col = colbase + cc;
        float v;
        if (col < 4096) {
            int j = col >> 7, o = col & 127;
            v = w2[(size_t)l * 524288 + j * 16384 + k * 128 + o];
        } else if (col < 4224) {
            v = b2[(size_t)l * 16384 + k * 128 + (col - 4096)];
        } else {
            v = rootw[(size_t)l * 16384 + k * 128 + (col - 4224)];
        }
        t[kk][cc] = (bf16)v;
    }
    __syncthreads();
    #pragma unroll
    for (int rep = 0; rep < 16; ++rep) {
        int c = rep * 4 + rr;
        bp[((size_t)((l * NCT + ct) * 64 + c)) * 128 + kt * 64 + cc] = t[cc][c];
    }
}

// ---------------- per-layer prep: z = (l? gelu(LN(h)) : h) -> bf16; newh = (l? h:0) + conv_b ----------------
__global__ void k_prep(const float* h, const float* lng, const float* lnb, const float* cbias,
                       int l, bf16* hbf, float* newh) {
    int n = blockIdx.x, lane = threadIdx.x;
    if (n >= NND) {  // zero-pad rows for the GEMM
        hbf[n * NH + lane] = (bf16)0.f;
        hbf[n * NH + lane + 64] = (bf16)0.f;
        return;
    }
    float v0 = h[n * NH + lane], v1 = h[n * NH + lane + 64];
    float z0 = v0, z1 = v1;
    if (l > 0) {
        float m = wred(v0 + v1) * (1.f / NH);
        float d0 = v0 - m, d1 = v1 - m;
        float var = wred(d0 * d0 + d1 * d1) * (1.f / NH);
        float rs = rsqrtf(var + 1e-5f);
        z0 = geluf(d0 * rs * lng[l * NH + lane] + lnb[l * NH + lane]);
        z1 = geluf(d1 * rs * lng[l * NH + lane + 64] + lnb[l * NH + lane + 64]);
    }
    hbf[n * NH + lane] = (bf16)z0;
    hbf[n * NH + lane + 64] = (bf16)z1;
    float b0 = cbias[l * NH + lane], b1 = cbias[l * NH + lane + 64];
    if (l > 0) { b0 += v0; b1 += v1; }
    newh[n * NH + lane] = b0;
    newh[n * NH + lane + 64] = b1;
}

// ---------------- MFMA GEMM: HW[896 x 4352](bf16) = hbf[896 x 128] @ Bpack ----------------
__global__ __launch_bounds__(256) void k_gemm(const bf16* __restrict__ hbf,
                                              const bf16* __restrict__ bp,
                                              bf16* __restrict__ HW) {
    int lane = threadIdx.x & 63, wv = threadIdx.x >> 6;
    int m0 = blockIdx.y * 64 + wv * 16;
    int ct = blockIdx.x;
    int r = lane & 15, q = lane >> 4;
    const bf16* Arow = hbf + (size_t)(m0 + r) * NH;
    const bf16* Bb = bp + ((size_t)ct * 64 + r) * NH;
    f32x4 a0 = {0.f,0.f,0.f,0.f}, a1 = a0, a2 = a0, a3 = a0;
    int q8 = q * 8;
    #pragma unroll
    for (int ks = 0; ks < 4; ++ks) {
        int kb = ks * 32 + q8;
        bf16x8 av = *(const bf16x8*)(Arow + kb);
        bf16x8 b0 = *(const bf16x8*)(Bb + 0 * 16 * NH + kb);
        bf16x8 b1 = *(const bf16x8*)(Bb + 1 * 16 * NH + kb);
        bf16x8 b2 = *(const bf16x8*)(Bb + 2 * 16 * NH + kb);
        bf16x8 b3 = *(const bf16x8*)(Bb + 3 * 16 * NH + kb);
        a0 = __builtin_amdgcn_mfma_f32_16x16x32_bf16(av, b0, a0, 0, 0, 0);
        a1 = __builtin_amdgcn_mfma_f32_16x16x32_bf16(av, b1, a1, 0, 0, 0);
        a2 = __builtin_amdgcn_mfma_f32_16x16x32_bf16(av, b2, a2, 0, 0, 0);
        a3 = __builtin_amdgcn_mfma_f32_16x16x32_bf16(av, b3, a3, 0, 0, 0);
    }
    int cb = ct * 64;
    #pragma unroll
    for (int reg = 0; reg < 4; ++reg) {
        bf16* Crow = HW + (size_t)(m0 + q * 4 + reg) * NCOLS + cb;
        Crow[0 * 16 + r] = (bf16)a0[reg];
        Crow[1 * 16 + r] = (bf16)a1[reg];
        Crow[2 * 16 + r] = (bf16)a2[reg];
        Crow[3 * 16 + r] = (bf16)a3[reg];
    }
}

// ---------------- edge contraction + aggregation (+root part) ----------------
__global__ void k_edge(const int* ei, const float* t1l, const bf16* __restrict__ HW,
                       float* newh) {
    __shared__ float ts[H3D];
    int blk = blockIdx.x, o = threadIdx.x;
    if (blk < NE) {
        if (o < H3D) ts[o] = t1l[blk * H3D + o];
        __syncthreads();
        int s = ei[blk], d = ei[NE + blk];
        const bf16* row = HW + (size_t)s * NCOLS;
        float acc = (float)row[4096 + o];            // b2-bias part
        #pragma unroll
        for (int j = 0; j < H3D; ++j) acc += ts[j] * (float)row[j * NH + o];
        atomicAdd(&newh[d * NH + o], acc);
    } else {
        int n = blk - NE;                            // root part: z@root_w
        atomicAdd(&newh[n * NH + o], (float)HW[(size_t)n * NCOLS + 4224 + o]);
    }
}

// ---------------- final gelu(LN) + positional concat -> t[856 x 160] ----------------
__global__ void k_fc(const float* h, const float* lng, const float* lnb, float* t) {
    int n = blockIdx.x, lane = threadIdx.x;
    float v0 = h[n * NH + lane], v1 = h[n * NH + lane + 64];
    float m = wred(v0 + v1) * (1.f / NH);
    float d0 = v0 - m, d1 = v1 - m;
    float var = wred(d0 * d0 + d1 * d1) * (1.f / NH);
    float rs = rsqrtf(var + 1e-5f);
    t[n * DD + lane]      = geluf(d0 * rs * lng[lane] + lnb[lane]);
    t[n * DD + lane + 64] = geluf(d1 * rs * lng[lane + 64] + lnb[lane + 64]);
    if (lane < PCD) {
        int qq = n % LSEQ;
        float twoi = (float)(lane & ~1);
        float ang = (float)qq * expf(-twoi * 0.28782313662425572f); // ln(10000)/32
        t[n * DD + NH + lane] = (lane & 1) ? cosf(ang) : sinf(ang);
    }
}

// ---------------- generic small GEMM: C = act(A @ B + bias) ----------------
__global__ void k_mm(const float* __restrict__ A, const float* __restrict__ B,
                     const float* __restrict__ bias, float* __restrict__ C,
                     int M, int K, int Ncols, int act) {
    int col = blockIdx.x * 64 + threadIdx.x;
    int row = blockIdx.y * 4 + threadIdx.y;
    if (row >= M || col >= Ncols) return;
    float acc = bias[col];
    const float* a = A + (size_t)row * K;
    const float* b = B + col;
    #pragma unroll 8
    for (int k = 0; k < K; ++k) acc += a[k] * b[(size_t)k * Ncols];
    if (act) acc = fmaxf(acc, 0.f);
    C[(size_t)row * Ncols + col] = acc;
}

// ---------------- attention: one block per (batch, head) ----------------
__global__ __launch_bounds__(128) void k_attn(const float* __restrict__ qkv,
                                              float* __restrict__ aout) {
    __shared__ float Ks[LSEQ * HDD], Vs[LSEQ * HDD];
    int bh = blockIdx.x;
    int b = bh >> 3, hh = bh & 7;
    int tid = threadIdx.x;
    for (int i = tid; i < LSEQ * HDD; i += 128) {
        int kq = i / HDD, dd = i - kq * HDD;
        const float* rowp = qkv + (size_t)(b * LSEQ + kq) * (3 * DD);
        Ks[i] = rowp[DD + hh * HDD + dd];
        Vs[i] = rowp[2 * DD + hh * HDD + dd];
    }
    __syncthreads();
    if (tid >= LSEQ) return;
    float qv[HDD];
    const float* qp = qkv + (size_t)(b * LSEQ + tid) * (3 * DD) + hh * HDD;
    #pragma unroll
    for (int dd = 0; dd < HDD; ++dd) qv[dd] = qp[dd];
    const float scale = 0.22360679774997896f;  // 1/sqrt(20)
    float mx = -1e30f;
    for (int k = 0; k < LSEQ; ++k) {
        float s = 0.f;
        #pragma unroll
        for (int dd = 0; dd < HDD; ++dd) s += qv[dd] * Ks[k * HDD + dd];
        mx = fmaxf(mx, s * scale);
    }
    float sum = 0.f, acc[HDD];
    #pragma unroll
    for (int dd = 0; dd < HDD; ++dd) acc[dd] = 0.f;
    for (int k = 0; k < LSEQ; ++k) {
        float s = 0.f;
        #pragma unroll
        for (int dd = 0; dd < HDD; ++dd) s += qv[dd] * Ks[k * HDD + dd];
        float p = expf(s * scale - mx);
        sum += p;
        #pragma unroll
        for (int dd = 0; dd < HDD; ++dd) acc[dd] += p * Vs[k * HDD + dd];
    }
    float inv = 1.f / sum;
    float* op = aout + (size_t)(b * LSEQ + tid) * DD + hh * HDD;
    #pragma unroll
    for (int dd = 0; dd < HDD; ++dd) op[dd] = acc[dd] * inv;
}

// ---------------- t = LN(t + delta) over 160, one wave per row ----------------
__global__ void k_addln(float* t, const float* delta, const float* g, const float* b) {
    int n = blockIdx.x, lane = threadIdx.x;
    int c0 = lane, c1 = lane + 64, c2 = lane + 128;
    float v0 = t[n * DD + c0] + delta[n * DD + c0];
    float v1 = t[n * DD + c1] + delta[n * DD + c1];
    float v2 = (lane < 32) ? (t[n * DD + c2] + delta[n * DD + c2]) : 0.f;
    float m = wred(v0 + v1 + v2) * (1.f / DD);
    float d0 = v0 - m, d1 = v1 - m, d2 = (lane < 32) ? (v2 - m) : 0.f;
    float var = wred(d0 * d0 + d1 * d1 + d2 * d2) * (1.f / DD);
    float rs = rsqrtf(var + 1e-5f);
    t[n * DD + c0] = d0 * rs * g[c0] + b[c0];
    t[n * DD + c1] = d1 * rs * g[c1] + b[c1];
    if (lane < 32) t[n * DD + c2] = d2 * rs * g[c2] + b[c2];
}

// ---------------- final linear -> f32 out ----------------
__global__ void k_lin(const float* t, const float* lw, const float* lb, float* out) {
    int idx = blockIdx.x * 256 + threadIdx.x;
    if (idx >= NND * NCLS) return;
    int n = idx / NCLS, c = idx - n * NCLS;
    float acc = lb[c];
    #pragma unroll 8
    for (int k = 0; k < DD; ++k) acc += t[n * DD + k] * lw[k * NCLS + c];
    out[idx] = acc;
}

extern "C" void kernel_launch(void* const* d_in, const int* in_sizes, int n_in,
                              void* d_out, int out_size, void* d_ws, size_t ws_size,
                              hipStream_t stream) {
    (void)in_sizes; (void)n_in; (void)out_size; (void)ws_size;
    const float* x      = (const float*)d_in[0];
    const float* eattr  = (const float*)d_in[1];
    const float* cheb_w = (const float*)d_in[2];
    const float* cheb_b = (const float*)d_in[3];
    const float* ee_w   = (const float*)d_in[4];
    const float* ee_b   = (const float*)d_in[5];
    const float* mlp_w1 = (const float*)d_in[6];
    const float* mlp_b1 = (const float*)d_in[7];
    const float* mlp_w2 = (const float*)d_in[8];
    const float* mlp_b2 = (const float*)d_in[9];
    const float* root_w = (const float*)d_in[10];
    const float* conv_b = (const float*)d_in[11];
    const float* ln_g   = (const float*)d_in[12];
    const float* ln_b   = (const float*)d_in[13];
    const float* ain_w  = (const float*)d_in[14];
    const float* ain_b  = (const float*)d_in[15];
    const float* aow    = (const float*)d_in[16];
    const float* aob    = (const float*)d_in[17];
    const float* ffw1   = (const float*)d_in[18];
    const float* ffb1   = (const float*)d_in[19];
    const float* ffw2   = (const float*)d_in[20];
    const float* ffb2   = (const float*)d_in[21];
    const float* t1g    = (const float*)d_in[22];
    const float* t1b    = (const float*)d_in[23];
    const float* t2g    = (const float*)d_in[24];
    const float* t2b    = (const float*)d_in[25];
    const float* lin_w  = (const float*)d_in[26];
    const float* lin_b  = (const float*)d_in[27];
    const int* sei      = (const int*)d_in[28];
    const int* ei       = (const int*)d_in[29];

    char* w = (char*)d_ws;
    size_t off = 0;
    auto alloc = [&](size_t bytes) -> void* {
        void* p = w + off;
        off += (bytes + 255) & ~(size_t)255;
        return p;
    };
    bf16*  bpack = (bf16*)alloc((size_t)NLAY * NCT * 64 * NH * 2);   // 11.1 MB
    float* t1all = (float*)alloc((size_t)NLAY * NE * H3D * 4);       // 3.7 MB
    float* ea    = (float*)alloc((size_t)NE * EHD * 4);
    float* hA    = (float*)alloc((size_t)NND * NH * 4);
    float* hB    = (float*)alloc((size_t)NND * NH * 4);
    bf16*  hbf   = (bf16*)alloc((size_t)NPAD * NH * 2);
    size_t z0 = off;
    float* deg   = (float*)alloc((size_t)NND * 4);
    float* wseq  = (float*)alloc((size_t)NSEQ * 4);
    float* tx1   = (float*)alloc((size_t)NND * NNF * 4);
    float* txt   = (float*)alloc((size_t)NND * NNF * 4);
    size_t zlen = off - z0;
    bf16*  HW    = (bf16*)alloc((size_t)NPAD * NCOLS * 2);           // 7.8 MB
    float* tbuf  = (float*)alloc((size_t)NND * DD * 4);
    float* qkv   = (float*)alloc((size_t)NND * 3 * DD * 4);
    float* abuf  = (float*)alloc((size_t)NND * DD * 4);
    float* proj  = (float*)alloc((size_t)NND * DD * 4);
    float* f1    = (float*)alloc((size_t)NND * FFD * 4);

    // zero the atomic-accumulated cheb-stage buffers
    hipMemsetAsync(w + z0, 0, zlen, stream);

    // --- ChebConv ---
    k_deg<<<(NSEQ + 255) / 256, 256, 0, stream>>>(sei, deg);
    k_w<<<(NSEQ + 255) / 256, 256, 0, stream>>>(sei, deg, wseq);
    k_lap<<<(NSEQ * NNF + 255) / 256, 256, 0, stream>>>(sei, wseq, x, tx1);
    k_lap<<<(NSEQ * NNF + 255) / 256, 256, 0, stream>>>(sei, wseq, tx1, txt);
    k_cheb<<<NND, NH, 0, stream>>>(x, tx1, txt, cheb_w, cheb_b, hA);

    // --- edge encoder, all-layer t1, weight pack ---
    k_ea<<<(NE * EHD + 255) / 256, 256, 0, stream>>>(eattr, ee_w, ee_b, ea);
    k_t1<<<(NLAY * NE * H3D + 255) / 256, 256, 0, stream>>>(ea, mlp_w1, mlp_b1, t1all);
    k_pack<<<dim3(2, NCT, NLAY), 256, 0, stream>>>(mlp_w2, mlp_b2, root_w, bpack);

    // --- 10 NNConv layers ---
    float* hcur = hA;
    float* hnxt = hB;
    for (int l = 0; l < NLAY; ++l) {
        k_prep<<<NPAD, 64, 0, stream>>>(hcur, ln_g, ln_b, conv_b, l, hbf, hnxt);
        k_gemm<<<dim3(NCT, 14), 256, 0, stream>>>(hbf, bpack + (size_t)l * NCT * 64 * NH, HW);
        k_edge<<<NE + NND, NH, 0, stream>>>(ei, t1all + (size_t)l * NE * H3D, HW, hnxt);
        float* tmp = hcur; hcur = hnxt; hnxt = tmp;
    }

    // --- final gelu(LN) + pos concat ---
    k_fc<<<NND, 64, 0, stream>>>(hcur, ln_g, ln_b, tbuf);

    // --- transformer encoder (3 layers, post-norm) ---
    for (int tl = 0; tl < TLAY; ++tl) {
        k_mm<<<dim3(8, 214), dim3(64, 4), 0, stream>>>(tbuf, ain_w + (size_t)tl * DD * 3 * DD,
                                                       ain_b + (size_t)tl * 3 * DD, qkv,
                                                       NND, DD, 3 * DD, 0);
        k_attn<<<BSZ * THD, 128, 0, stream>>>(qkv, abuf);
        k_mm<<<dim3(3, 214), dim3(64, 4), 0, stream>>>(abuf, aow + (size_t)tl * DD * DD,
                                                       aob + (size_t)tl * DD, proj,
                                                       NND, DD, DD, 0);
        k_addln<<<NND, 64, 0, stream>>>(tbuf, proj, t1g + (size_t)tl * DD, t1b + (size_t)tl * DD);
        k_mm<<<dim3(4, 214), dim3(64, 4), 0, stream>>>(tbuf, ffw1 + (size_t)tl * DD * FFD,
                                                       ffb1 + (size_t)tl * FFD, f1,
                                                       NND, DD, FFD, 1);
        k_mm<<<dim3(3, 214), dim3(64, 4), 0, stream>>>(f1, ffw2 + (size_t)tl * FFD * DD,
                                                       ffb2 + (size_t)tl * DD, proj,
                                                       NND, FFD, DD, 0);
        k_addln<<<NND, 64, 0, stream>>>(tbuf, proj, t2g + (size_t)tl * DD, t2b + (size_t)tl * DD);
    }

    // --- final linear ---
    k_lin<<<(NND * NCLS + 255) / 256, 256, 0, stream>>>(tbuf, lin_w, lin_b, (float*)d_out);
}